// Round 3
// baseline (102.918 us; speedup 1.0000x reference)
//
#include <hip/hip_runtime.h>
#include <math.h>

// Problem constants (B=2, N=512, E=128, H=8, D=16)
#define BATCH 2
#define NSEQ  512
#define EDIM  128
#define HNUM  8
#define DDIM  16
#define MROWS (BATCH*NSEQ)   // 1024

// ---------------------------------------------------------------------------
// Fully fused: per-row QKV projection + edge-weighted attention + output
// projection, ONE kernel, one block (512 thr = 8 waves) per (b,n) row.
//
// Row-locality: dots[b,h,n,m] uses q,k of row n only (reference broadcasts
// the query node's key over m), v of row n only, and e-row n. qkv[bn] depends
// only on x[bn]. So everything for output row bn is computable in one block.
//
// LeakyReLU identity (exact): lrelu(t) = 0.505*t + 0.495*|t|. The linear part
// is analytically separable, so the O(N*D) inner loops are 2 VALU ops/pair:
//   t = fma(s,w,b); acc = fma(c, |t|, acc)     (|t| = free VOP3 modifier)
// ---------------------------------------------------------------------------
__global__ __launch_bounds__(512, 4)
void fused_attn(const float* __restrict__ x,    const float* __restrict__ e,
                const float* __restrict__ wqkv, const float* __restrict__ wekv,
                const float* __restrict__ bekv, const float* __restrict__ wprj,
                const float* __restrict__ bprj, float* __restrict__ out) {
    __shared__ float xs[EDIM];          // x row
    __shared__ float qkvs[3 * EDIM];    // q|k|v row (384)
    __shared__ float hat_s[EDIM];       // attention output row

    const int tid  = threadIdx.x;
    const int lane = tid & 63;
    const int h    = tid >> 6;          // wave id == head
    const int bn   = blockIdx.x;        // b*N + n

    // ---- hoist e-row loads: latency hides behind the qkv stage ----
    const float* erow = e + (size_t)bn * NSEQ;
    float ev[NSEQ / 64];
    #pragma unroll
    for (int c = 0; c < NSEQ / 64; ++c)
        ev[c] = erow[c * 64 + lane];                 // coalesced

    // ---- stage x row into LDS ----
    if (tid < 32)
        ((float4*)xs)[tid] = ((const float4*)(x + (size_t)bn * EDIM))[tid];
    __syncthreads();

    // ---- per-row QKV projection: 384 outputs, 4-way k-split ----
    {
        const int o   = tid >> 2;                    // 0..127
        const int seg = tid & 3;                     // 32-float k slice
        #pragma unroll
        for (int rep = 0; rep < 3; ++rep) {
            const int oo = o + rep * 128;
            const float4* wp = (const float4*)(wqkv + (size_t)oo * EDIM + seg * 32);
            const float4* xp = (const float4*)(xs + seg * 32);
            float s = 0.f;
            #pragma unroll
            for (int j = 0; j < 8; ++j) {
                float4 w4 = wp[j], x4 = xp[j];
                s = fmaf(w4.x, x4.x, s);
                s = fmaf(w4.y, x4.y, s);
                s = fmaf(w4.z, x4.z, s);
                s = fmaf(w4.w, x4.w, s);
            }
            s += __shfl_xor(s, 1, 64);               // quad-local reduce
            s += __shfl_xor(s, 2, 64);
            if (seg == 0) qkvs[oo] = s;
        }
    }
    __syncthreads();

    const float* qrow = qkvs + h * DDIM;
    const float* krow = qrow + EDIM;
    const float* vrow = qrow + 2 * EDIM;

    const float SC = 0.25f * 1.44269504088896340736f;  // 1/sqrt(D) * log2(e)

    // ---- per-head precompute ----
    float wk[DDIM], bk[DDIM], cd[DDIM];
    float qk = 0.f, qwk = 0.f, qbk = 0.f;
    #pragma unroll
    for (int d = 0; d < DDIM; ++d) {
        float q = qrow[d];                           // LDS broadcast
        qk  = fmaf(q, krow[d], qk);
        wk[d] = wekv[h * DDIM + d];
        bk[d] = bekv[h * DDIM + d];
        qwk = fmaf(q, wk[d], qwk);
        qbk = fmaf(q, bk[d], qbk);
        cd[d] = 0.495f * SC * q;
    }
    const float Alin = SC * 0.505f * qwk;
    const float base = SC * (qk + 0.505f * qbk);

    // ---- pass 1: dots (log2 domain) + wave max ----
    float dots[NSEQ / 64];
    float lmax = -1e30f;
    #pragma unroll
    for (int c = 0; c < NSEQ / 64; ++c) {
        float s = ev[c];
        float dot = fmaf(s, Alin, base);
        #pragma unroll
        for (int d = 0; d < DDIM; ++d) {
            float t = fmaf(s, wk[d], bk[d]);
            dot = fmaf(cd[d], fabsf(t), dot);
        }
        dots[c] = dot;
        lmax = fmaxf(lmax, dot);
    }
    #pragma unroll
    for (int off = 32; off >= 1; off >>= 1)
        lmax = fmaxf(lmax, __shfl_xor(lmax, off, 64));

    // ---- pass 2: p = exp2(dot-max); accumulate sums ----
    float wvv[DDIM], bv[DDIM], racc[DDIM];
    #pragma unroll
    for (int d = 0; d < DDIM; ++d) {
        wvv[d]  = wekv[EDIM + h * DDIM + d];
        bv[d]   = bekv[EDIM + h * DDIM + d];
        racc[d] = 0.f;
    }
    float sp = 0.f, spe = 0.f;
    #pragma unroll
    for (int c = 0; c < NSEQ / 64; ++c) {
        float p = __builtin_amdgcn_exp2f(dots[c] - lmax);
        float s = ev[c];
        sp  += p;
        spe  = fmaf(p, s, spe);
        float pm = 0.495f * p;
        #pragma unroll
        for (int d = 0; d < DDIM; ++d) {
            float t = fmaf(s, wvv[d], bv[d]);
            racc[d] = fmaf(pm, fabsf(t), racc[d]);
        }
    }

    // ---- butterfly reduce sp, spe, racc[16] ----
    #pragma unroll
    for (int off = 1; off < 64; off <<= 1) {
        sp  += __shfl_xor(sp,  off, 64);
        spe += __shfl_xor(spe, off, 64);
        #pragma unroll
        for (int d = 0; d < DDIM; ++d)
            racc[d] += __shfl_xor(racc[d], off, 64);
    }

    // lane d selects racc[d]; add analytic linear part; write hat to LDS
    float rsel = racc[0];
    #pragma unroll
    for (int d = 1; d < DDIM; ++d) rsel = (lane == d) ? racc[d] : rsel;
    if (lane < DDIM) {
        float wvs = wekv[EDIM + h * DDIM + lane];
        float bvs = bekv[EDIM + h * DDIM + lane];
        float acc = rsel + 0.505f * fmaf(wvs, spe, bvs * sp);
        hat_s[h * DDIM + lane] = vrow[lane] + acc / sp;
    }
    __syncthreads();

    // ---- output projection: out[c] = b[c] + hat . wprj[c,:] ----
    const int c    = tid >> 2;
    const int quad = tid & 3;
    const float4* wp = (const float4*)(wprj + (size_t)c * EDIM + quad * 32);
    const float4* hp = (const float4*)(hat_s + quad * 32);
    float s = 0.f;
    #pragma unroll
    for (int j = 0; j < 8; ++j) {
        float4 w4 = wp[j], h4 = hp[j];
        s = fmaf(w4.x, h4.x, s);
        s = fmaf(w4.y, h4.y, s);
        s = fmaf(w4.z, h4.z, s);
        s = fmaf(w4.w, h4.w, s);
    }
    s += __shfl_xor(s, 1, 64);
    s += __shfl_xor(s, 2, 64);
    if (quad == 0)
        out[(size_t)bn * EDIM + c] = s + bprj[c];
}

// ---------------------------------------------------------------------------
extern "C" void kernel_launch(void* const* d_in, const int* in_sizes, int n_in,
                              void* d_out, int out_size, void* d_ws, size_t ws_size,
                              hipStream_t stream) {
    const float* x     = (const float*)d_in[0];  // [B,N,128]
    const float* e     = (const float*)d_in[1];  // [B,N,N]
    const float* w_qkv = (const float*)d_in[2];  // [384,128]
    const float* w_ekv = (const float*)d_in[3];  // [256,1]
    const float* b_ekv = (const float*)d_in[4];  // [256]
    const float* w_prj = (const float*)d_in[5];  // [128,128]
    const float* b_prj = (const float*)d_in[6];  // [128]
    float* out = (float*)d_out;

    fused_attn<<<MROWS, 512, 0, stream>>>(x, e, w_qkv, w_ekv, b_ekv,
                                          w_prj, b_prj, out);
}

// Round 4
// 90.837 us; speedup vs baseline: 1.1330x; 1.1330x over previous
//
#include <hip/hip_runtime.h>
#include <math.h>

// Problem constants (B=2, N=512, E=128, H=8, D=16)
#define BATCH 2
#define NSEQ  512
#define EDIM  128
#define HNUM  8
#define DDIM  16
#define MROWS (BATCH*NSEQ)   // 1024

// ---------------------------------------------------------------------------
// QV GEMM: qv[1024,256] = x[1024,128] @ [w_q; w_v][256,128]^T
// (k projection dropped: q.k is constant over m -> cancels in softmax.)
// qv cols 0..127 = q (w rows 0..127), cols 128..255 = v (w rows 256..383).
// Tile 32x64, 256 threads, micro 2x4, XOR-swizzled float4 LDS (<=2-way alias).
// ---------------------------------------------------------------------------
__global__ __launch_bounds__(256)
void qv_gemm(const float* __restrict__ x, const float* __restrict__ w,
             float* __restrict__ qv) {
    __shared__ float4 As[32 * 32];   // 16 KB
    __shared__ float4 Bs[64 * 32];   // 32 KB

    const int tid  = threadIdx.x;
    const int row0 = blockIdx.y * 32;
    const int bx   = blockIdx.x;                 // 0..3
    const int wr0  = (bx >> 1) * 256 + (bx & 1) * 64;   // w row base (skip k rows)
    const int cc0  = (bx >> 1) * 128 + (bx & 1) * 64;   // out col base

    #pragma unroll
    for (int it = 0; it < 4; ++it) {             // A: 32 rows x 32 float4
        int idx = tid + it * 256;
        int r = idx >> 5, k4 = idx & 31;
        As[r * 32 + (k4 ^ ((r >> 2) & 7))] =
            ((const float4*)(x + (size_t)(row0 + r) * 128))[k4];
    }
    #pragma unroll
    for (int it = 0; it < 8; ++it) {             // B: 64 rows x 32 float4
        int idx = tid + it * 256;
        int r = idx >> 5, k4 = idx & 31;
        Bs[r * 32 + (k4 ^ ((r >> 2) & 7))] =
            ((const float4*)(w + (size_t)(wr0 + r) * 128))[k4];
    }
    __syncthreads();

    const int ty  = tid >> 4;
    const int tx  = tid & 15;
    const int ra  = ty * 2;
    const int swa = (ra >> 2) & 7;
    const int rb  = tx * 4;
    const int swb = tx & 7;

    float acc[2][4] = {};
    #pragma unroll
    for (int k4 = 0; k4 < 32; ++k4) {
        float4 a0 = As[ ra      * 32 + (k4 ^ swa)];
        float4 a1 = As[(ra + 1) * 32 + (k4 ^ swa)];
        float4 bv4[4];
        #pragma unroll
        for (int j = 0; j < 4; ++j)
            bv4[j] = Bs[(rb + j) * 32 + (k4 ^ swb)];
        #pragma unroll
        for (int j = 0; j < 4; ++j) {
            acc[0][j] = fmaf(a0.x, bv4[j].x, acc[0][j]);
            acc[0][j] = fmaf(a0.y, bv4[j].y, acc[0][j]);
            acc[0][j] = fmaf(a0.z, bv4[j].z, acc[0][j]);
            acc[0][j] = fmaf(a0.w, bv4[j].w, acc[0][j]);
            acc[1][j] = fmaf(a1.x, bv4[j].x, acc[1][j]);
            acc[1][j] = fmaf(a1.y, bv4[j].y, acc[1][j]);
            acc[1][j] = fmaf(a1.z, bv4[j].z, acc[1][j]);
            acc[1][j] = fmaf(a1.w, bv4[j].w, acc[1][j]);
        }
    }

    #pragma unroll
    for (int i = 0; i < 2; ++i) {
        float* crow = qv + (size_t)(row0 + ra + i) * 256 + cc0 + rb;
        *(float4*)crow = make_float4(acc[i][0], acc[i][1], acc[i][2], acc[i][3]);
    }
}

// ---------------------------------------------------------------------------
// Attention + output projection. One block (512 thr = 8 waves) per (b,n) row;
// wave h = head h; lane covers 8 m-values.
//
// Exact identities used:
//   lrelu(t) = 0.505*t + 0.495*|t|
//   q.k and 0.505*q.bk are m-independent -> cancel in softmax (dropped)
//   no max-subtraction: exp2 in fp32 has the range; scale cancels in acc/sp
// Single pass per m: dot -> p = exp2(dot) -> accumulate {sp, spe, racc[16]}.
// Reduction: sp/spe butterfly; racc via LDS transpose (2-way alias = free).
// ---------------------------------------------------------------------------
__global__ __launch_bounds__(512)
void attn_proj(const float* __restrict__ qv,   const float* __restrict__ e,
               const float* __restrict__ wekv, const float* __restrict__ bekv,
               const float* __restrict__ wprj, const float* __restrict__ bprj,
               float* __restrict__ out) {
    __shared__ float hat_s[EDIM];
    __shared__ float red[HNUM][DDIM][65];   // [wave][d][lane], stride 65: 2-way banks

    const int tid  = threadIdx.x;
    const int lane = tid & 63;
    const int h    = __builtin_amdgcn_readfirstlane(tid >> 6);  // wave-uniform head
    const int bn   = blockIdx.x;                                // b*N + n

    const float* qrow = qv + (size_t)bn * 256 + h * DDIM;
    const float* vrow = qrow + 128;
    const float* erow = e + (size_t)bn * NSEQ;

    const float SC = 0.25f * 1.44269504088896340736f;  // 1/sqrt(D) * log2(e)

    // ---- per-head precompute (all wave-uniform -> scalar loads) ----
    float wk[DDIM], bk[DDIM], cd[DDIM], wvv[DDIM], bv[DDIM];
    float qwk = 0.f;
    #pragma unroll
    for (int d = 0; d < DDIM; ++d) {
        float q = qrow[d];
        wk[d]  = wekv[h * DDIM + d];
        bk[d]  = bekv[h * DDIM + d];
        wvv[d] = wekv[EDIM + h * DDIM + d];
        bv[d]  = bekv[EDIM + h * DDIM + d];
        qwk    = fmaf(q, wk[d], qwk);
        cd[d]  = 0.495f * SC * q;
    }
    const float Alin = SC * 0.505f * qwk;

    // ---- e row: 2 vectorized loads = this lane's 8 m-values ----
    float4 e0 = ((const float4*)erow)[lane];
    float4 e1 = ((const float4*)erow)[lane + 64];
    float evs[8] = {e0.x, e0.y, e0.z, e0.w, e1.x, e1.y, e1.z, e1.w};

    // ---- single fused pass over m ----
    float racc[DDIM];
    #pragma unroll
    for (int d = 0; d < DDIM; ++d) racc[d] = 0.f;
    float sp = 0.f, spe = 0.f;
    #pragma unroll
    for (int c = 0; c < 8; ++c) {
        float s = evs[c];
        float dot = s * Alin;
        #pragma unroll
        for (int d = 0; d < DDIM; ++d) {
            float t = fmaf(s, wk[d], bk[d]);
            dot = fmaf(cd[d], fabsf(t), dot);   // |t| = free VOP3 modifier
        }
        float p = __builtin_amdgcn_exp2f(dot);
        sp  += p;
        spe  = fmaf(p, s, spe);
        #pragma unroll
        for (int d = 0; d < DDIM; ++d) {
            float t = fmaf(s, wvv[d], bv[d]);
            racc[d] = fmaf(p, fabsf(t), racc[d]);  // 0.495 applied after reduce
        }
    }

    // ---- sp/spe butterfly ----
    #pragma unroll
    for (int off = 1; off < 64; off <<= 1) {
        sp  += __shfl_xor(sp,  off, 64);
        spe += __shfl_xor(spe, off, 64);
    }

    // ---- racc transpose reduce: lane l ends with total[l&15] ----
    #pragma unroll
    for (int d = 0; d < DDIM; ++d)
        red[h][d][lane] = racc[d];
    __syncthreads();
    const int rc = lane & 15, rg = lane >> 4;
    float part = 0.f;
    #pragma unroll
    for (int j = 0; j < 16; ++j)
        part += red[h][rc][rg * 16 + j];
    part += __shfl_xor(part, 16, 64);
    part += __shfl_xor(part, 32, 64);

    if (lane < DDIM) {
        float wvs = wekv[EDIM + h * DDIM + lane];
        float bvs = bekv[EDIM + h * DDIM + lane];
        float acc = 0.495f * part + 0.505f * fmaf(wvs, spe, bvs * sp);
        hat_s[h * DDIM + lane] = vrow[lane] + acc / sp;
    }
    __syncthreads();

    // ---- output projection: out[c] = b[c] + hat . wprj[c,:] ----
    const int c    = tid >> 2;
    const int quad = tid & 3;
    const float4* wp = (const float4*)(wprj + (size_t)c * EDIM + quad * 32);
    const float4* hp = (const float4*)(hat_s + quad * 32);
    float s = 0.f;
    #pragma unroll
    for (int j = 0; j < 8; ++j) {
        float4 w4 = wp[j], h4 = hp[j];
        s = fmaf(w4.x, h4.x, s);
        s = fmaf(w4.y, h4.y, s);
        s = fmaf(w4.z, h4.z, s);
        s = fmaf(w4.w, h4.w, s);
    }
    s += __shfl_xor(s, 1, 64);
    s += __shfl_xor(s, 2, 64);
    if (quad == 0)
        out[(size_t)bn * EDIM + c] = s + bprj[c];
}

// ---------------------------------------------------------------------------
extern "C" void kernel_launch(void* const* d_in, const int* in_sizes, int n_in,
                              void* d_out, int out_size, void* d_ws, size_t ws_size,
                              hipStream_t stream) {
    const float* x     = (const float*)d_in[0];  // [B,N,128]
    const float* e     = (const float*)d_in[1];  // [B,N,N]
    const float* w_qkv = (const float*)d_in[2];  // [384,128]
    const float* w_ekv = (const float*)d_in[3];  // [256,1]
    const float* b_ekv = (const float*)d_in[4];  // [256]
    const float* w_prj = (const float*)d_in[5];  // [128,128]
    const float* b_prj = (const float*)d_in[6];  // [128]
    float* out = (float*)d_out;

    float* qv = (float*)d_ws;                    // [1024, 256]

    qv_gemm<<<dim3(4, MROWS / 32), 256, 0, stream>>>(x, w_qkv, qv);

    attn_proj<<<MROWS, 512, 0, stream>>>(qv, e, w_ekv, b_ekv, w_prj, b_prj, out);
}

// Round 5
// 84.985 us; speedup vs baseline: 1.2110x; 1.0689x over previous
//
#include <hip/hip_runtime.h>
#include <math.h>

// Problem constants (B=2, N=512, E=128, H=8, D=16)
#define BATCH 2
#define NSEQ  512
#define EDIM  128
#define HNUM  8
#define DDIM  16
#define MROWS (BATCH*NSEQ)   // 1024

// ---------------------------------------------------------------------------
// QV GEMM: qv[1024,256] = x[1024,128] @ [w_q; w_v][256,128]^T
// (k projection dropped: q.k is constant over m -> cancels in softmax.)
// Tile 32x64, 256 threads, micro 2x4, XOR-swizzled float4 LDS (<=2-way alias).
// ---------------------------------------------------------------------------
__global__ __launch_bounds__(256)
void qv_gemm(const float* __restrict__ x, const float* __restrict__ w,
             float* __restrict__ qv) {
    __shared__ float4 As[32 * 32];   // 16 KB
    __shared__ float4 Bs[64 * 32];   // 32 KB

    const int tid  = threadIdx.x;
    const int row0 = blockIdx.y * 32;
    const int bx   = blockIdx.x;                        // 0..3
    const int wr0  = (bx >> 1) * 256 + (bx & 1) * 64;   // w row base (skip k rows)
    const int cc0  = (bx >> 1) * 128 + (bx & 1) * 64;   // out col base

    #pragma unroll
    for (int it = 0; it < 4; ++it) {             // A: 32 rows x 32 float4
        int idx = tid + it * 256;
        int r = idx >> 5, k4 = idx & 31;
        As[r * 32 + (k4 ^ ((r >> 2) & 7))] =
            ((const float4*)(x + (size_t)(row0 + r) * 128))[k4];
    }
    #pragma unroll
    for (int it = 0; it < 8; ++it) {             // B: 64 rows x 32 float4
        int idx = tid + it * 256;
        int r = idx >> 5, k4 = idx & 31;
        Bs[r * 32 + (k4 ^ ((r >> 2) & 7))] =
            ((const float4*)(w + (size_t)(wr0 + r) * 128))[k4];
    }
    __syncthreads();

    const int ty  = tid >> 4;
    const int tx  = tid & 15;
    const int ra  = ty * 2;
    const int swa = (ra >> 2) & 7;
    const int rb  = tx * 4;
    const int swb = tx & 7;

    float acc[2][4] = {};
    #pragma unroll
    for (int k4 = 0; k4 < 32; ++k4) {
        float4 a0 = As[ ra      * 32 + (k4 ^ swa)];
        float4 a1 = As[(ra + 1) * 32 + (k4 ^ swa)];
        float4 bv4[4];
        #pragma unroll
        for (int j = 0; j < 4; ++j)
            bv4[j] = Bs[(rb + j) * 32 + (k4 ^ swb)];
        #pragma unroll
        for (int j = 0; j < 4; ++j) {
            acc[0][j] = fmaf(a0.x, bv4[j].x, acc[0][j]);
            acc[0][j] = fmaf(a0.y, bv4[j].y, acc[0][j]);
            acc[0][j] = fmaf(a0.z, bv4[j].z, acc[0][j]);
            acc[0][j] = fmaf(a0.w, bv4[j].w, acc[0][j]);
            acc[1][j] = fmaf(a1.x, bv4[j].x, acc[1][j]);
            acc[1][j] = fmaf(a1.y, bv4[j].y, acc[1][j]);
            acc[1][j] = fmaf(a1.z, bv4[j].z, acc[1][j]);
            acc[1][j] = fmaf(a1.w, bv4[j].w, acc[1][j]);
        }
    }

    #pragma unroll
    for (int i = 0; i < 2; ++i) {
        float* crow = qv + (size_t)(row0 + ra + i) * 256 + cc0 + rb;
        *(float4*)crow = make_float4(acc[i][0], acc[i][1], acc[i][2], acc[i][3]);
    }
}

// ---------------------------------------------------------------------------
// Attention + output projection, 2 rows per block.
// 1024 thr = 16 waves; wave w -> (row = w>>3, head = w&7); lane covers 8 m.
// Exact identities: lrelu(t)=0.505t+0.495|t|; q.k and m-independent linear
// terms cancel in softmax; no max-subtraction (fp32 exp2 range suffices).
// Out-projection: k-split 8, each thread's wprj slice (4 float4) serves BOTH
// rows (halves wprj traffic vs 1-row blocks); loads hoisted above the
// reduction sequence to hide L2 latency.
// ---------------------------------------------------------------------------
__global__ __launch_bounds__(1024)
void attn_proj(const float* __restrict__ qv,   const float* __restrict__ e,
               const float* __restrict__ wekv, const float* __restrict__ bekv,
               const float* __restrict__ wprj, const float* __restrict__ bprj,
               float* __restrict__ out) {
    __shared__ float hat_s[2][EDIM];
    __shared__ float red[16][DDIM][65];   // per-wave transpose slices, 2-way banks

    const int tid  = threadIdx.x;
    const int lane = tid & 63;
    const int wv   = tid >> 6;                                   // 0..15
    const int h    = __builtin_amdgcn_readfirstlane(wv & 7);     // head
    const int r    = __builtin_amdgcn_readfirstlane(wv >> 3);    // row in pair
    const int bn   = blockIdx.x * 2 + r;

    // ---- e row: this lane's 8 m-values (2 coalesced float4 loads) ----
    const float* erow = e + (size_t)bn * NSEQ;
    float4 e0 = ((const float4*)erow)[lane];
    float4 e1 = ((const float4*)erow)[lane + 64];
    float evs[8] = {e0.x, e0.y, e0.z, e0.w, e1.x, e1.y, e1.z, e1.w};

    const float* qrow = qv + (size_t)bn * 256 + h * DDIM;
    const float* vrow = qrow + 128;

    const float SC = 0.25f * 1.44269504088896340736f;  // 1/sqrt(D) * log2(e)

    // ---- per-head precompute (wave-uniform -> scalar loads) ----
    float wk[DDIM], bk[DDIM], cd[DDIM], wvv[DDIM], bv[DDIM];
    float qwk = 0.f;
    #pragma unroll
    for (int d = 0; d < DDIM; ++d) {
        float q = qrow[d];
        wk[d]  = wekv[h * DDIM + d];
        bk[d]  = bekv[h * DDIM + d];
        wvv[d] = wekv[EDIM + h * DDIM + d];
        bv[d]  = bekv[EDIM + h * DDIM + d];
        qwk    = fmaf(q, wk[d], qwk);
        cd[d]  = 0.495f * SC * q;
    }
    const float Alin = SC * 0.505f * qwk;

    // ---- single fused pass over this lane's 8 m-values ----
    float racc[DDIM];
    #pragma unroll
    for (int d = 0; d < DDIM; ++d) racc[d] = 0.f;
    float sp = 0.f, spe = 0.f;
    #pragma unroll
    for (int c = 0; c < 8; ++c) {
        float s = evs[c];
        float dot = s * Alin;
        #pragma unroll
        for (int d = 0; d < DDIM; ++d) {
            float t = fmaf(s, wk[d], bk[d]);
            dot = fmaf(cd[d], fabsf(t), dot);   // |t| = free VOP3 modifier
        }
        float p = __builtin_amdgcn_exp2f(dot);
        sp  += p;
        spe  = fmaf(p, s, spe);
        #pragma unroll
        for (int d = 0; d < DDIM; ++d) {
            float t = fmaf(s, wvv[d], bv[d]);
            racc[d] = fmaf(p, fabsf(t), racc[d]);  // 0.495 applied after reduce
        }
    }

    // ---- hoist wprj loads: latency hides behind reduce + barrier ----
    const int oc  = tid >> 3;     // 0..127 output column
    const int seg = tid & 7;      // 16-k slice
    const float4* wp = (const float4*)(wprj + (size_t)oc * EDIM + seg * 16);
    float4 w4[4];
    #pragma unroll
    for (int j = 0; j < 4; ++j) w4[j] = wp[j];

    // ---- sp/spe butterfly ----
    #pragma unroll
    for (int off = 1; off < 64; off <<= 1) {
        sp  += __shfl_xor(sp,  off, 64);
        spe += __shfl_xor(spe, off, 64);
    }

    // ---- racc transpose reduce within own wave slice (no barrier needed) ----
    #pragma unroll
    for (int d = 0; d < DDIM; ++d)
        red[wv][d][lane] = racc[d];
    const int rc = lane & 15, rg = lane >> 4;
    float part = 0.f;
    #pragma unroll
    for (int j = 0; j < 16; ++j)
        part += red[wv][rc][rg * 16 + j];
    part += __shfl_xor(part, 16, 64);
    part += __shfl_xor(part, 32, 64);

    if (lane < DDIM) {
        float wvs = wekv[EDIM + h * DDIM + lane];
        float bvs = bekv[EDIM + h * DDIM + lane];
        float acc = 0.495f * part + 0.505f * fmaf(wvs, spe, bvs * sp);
        hat_s[r][h * DDIM + lane] = vrow[lane] + acc / sp;
    }
    __syncthreads();

    // ---- output projection: both rows from one wprj slice ----
    const float4* h0 = (const float4*)(&hat_s[0][seg * 16]);
    const float4* h1 = (const float4*)(&hat_s[1][seg * 16]);
    float s0 = 0.f, s1 = 0.f;
    #pragma unroll
    for (int j = 0; j < 4; ++j) {
        float4 a = w4[j], p0 = h0[j], p1 = h1[j];
        s0 = fmaf(a.x, p0.x, s0); s0 = fmaf(a.y, p0.y, s0);
        s0 = fmaf(a.z, p0.z, s0); s0 = fmaf(a.w, p0.w, s0);
        s1 = fmaf(a.x, p1.x, s1); s1 = fmaf(a.y, p1.y, s1);
        s1 = fmaf(a.z, p1.z, s1); s1 = fmaf(a.w, p1.w, s1);
    }
    #pragma unroll
    for (int off = 1; off < 8; off <<= 1) {
        s0 += __shfl_xor(s0, off, 64);
        s1 += __shfl_xor(s1, off, 64);
    }
    if (seg < 2) {
        float v = (seg ? s1 : s0) + bprj[oc];
        out[(size_t)(blockIdx.x * 2 + seg) * EDIM + oc] = v;
    }
}

// ---------------------------------------------------------------------------
extern "C" void kernel_launch(void* const* d_in, const int* in_sizes, int n_in,
                              void* d_out, int out_size, void* d_ws, size_t ws_size,
                              hipStream_t stream) {
    const float* x     = (const float*)d_in[0];  // [B,N,128]
    const float* e     = (const float*)d_in[1];  // [B,N,N]
    const float* w_qkv = (const float*)d_in[2];  // [384,128]
    const float* w_ekv = (const float*)d_in[3];  // [256,1]
    const float* b_ekv = (const float*)d_in[4];  // [256]
    const float* w_prj = (const float*)d_in[5];  // [128,128]
    const float* b_prj = (const float*)d_in[6];  // [128]
    float* out = (float*)d_out;

    float* qv = (float*)d_ws;                    // [1024, 256]

    qv_gemm<<<dim3(4, MROWS / 32), 256, 0, stream>>>(x, w_qkv, qv);

    attn_proj<<<MROWS / 2, 1024, 0, stream>>>(qv, e, w_ekv, b_ekv,
                                              w_prj, b_prj, out);
}

// Round 6
// 78.965 us; speedup vs baseline: 1.3033x; 1.0762x over previous
//
#include <hip/hip_runtime.h>
#include <math.h>

// Problem constants (B=2, N=512, E=128, H=8, D=16)
#define BATCH 2
#define NSEQ  512
#define EDIM  128
#define HNUM  8
#define DDIM  16
#define MROWS (BATCH*NSEQ)   // 1024

// ---------------------------------------------------------------------------
// Single fused kernel: QV projection + edge-weighted attention + output
// projection. Grid = 256 blocks (1/CU), 1024 thr = 16 waves, 4 rows/block
// processed as two 2-row rounds.
//
// Weight economics (the R3 lesson): per block w_q+w_v = 128 KB (k-split 4,
// no duplication) + wprj 64 KB reused across both rounds = 48 KB/row.
// Aggregate 48 MB ~= 1.2 us of L2 traffic, hidden behind e prefetch.
//
// Exact identities: lrelu(t) = 0.505 t + 0.495|t| (|t| free VOP3 modifier);
// q.k and m-independent linear terms cancel in softmax; no max-subtraction
// (fp32 exp2 range suffices, scale cancels in acc/sp).
// ---------------------------------------------------------------------------
__global__ __launch_bounds__(1024)
void attn_all(const float* __restrict__ x,    const float* __restrict__ e,
              const float* __restrict__ wqkv, const float* __restrict__ wekv,
              const float* __restrict__ bekv, const float* __restrict__ wprj,
              const float* __restrict__ bprj, float* __restrict__ out) {
    __shared__ float xs[4][EDIM];          // 4 x rows           (2 KB)
    __shared__ float qvs[4][256];          // q|v per row        (4 KB)
    __shared__ float hat_s[2][2][EDIM];    // double-buffered    (2 KB)
    __shared__ float red[16][DDIM][65];    // per-wave transpose (66.6 KB)

    const int tid  = threadIdx.x;
    const int lane = tid & 63;
    const int wv   = tid >> 6;                                   // 0..15
    const int h    = __builtin_amdgcn_readfirstlane(wv & 7);     // head
    const int r    = __builtin_amdgcn_readfirstlane(wv >> 3);    // row in pair
    const int bn0  = blockIdx.x * 4;

    // ---- prefetch BOTH rounds' e rows (hides behind the qv phase) ----
    const float* er0 = e + (size_t)(bn0 + r)     * NSEQ;
    const float* er1 = e + (size_t)(bn0 + 2 + r) * NSEQ;
    float4 epre[2][2];
    epre[0][0] = ((const float4*)er0)[lane];
    epre[0][1] = ((const float4*)er0)[lane + 64];
    epre[1][0] = ((const float4*)er1)[lane];
    epre[1][1] = ((const float4*)er1)[lane + 64];

    // ---- stage 4 x rows into LDS ----
    if (tid < 128) {
        int rr = tid >> 5, c4 = tid & 31;
        ((float4*)xs[rr])[c4] = ((const float4*)(x + (size_t)(bn0 + rr) * EDIM))[c4];
    }
    __syncthreads();

    // ---- QV phase: oc = tid>>2 (0..255: 0-127 q, 128-255 v), seg = tid&3 ----
    {
        const int oc   = tid >> 2;
        const int seg  = tid & 3;
        const int wrow = (oc < 128) ? oc : oc + 128;   // skip k rows of w_qkv
        const float4* wp = (const float4*)(wqkv + (size_t)wrow * EDIM + seg * 32);
        float4 wreg[8];
        #pragma unroll
        for (int j = 0; j < 8; ++j) wreg[j] = wp[j];
        #pragma unroll
        for (int rr = 0; rr < 4; ++rr) {
            const float4* xp = (const float4*)(xs[rr] + seg * 32);
            float s = 0.f;
            #pragma unroll
            for (int j = 0; j < 8; ++j) {
                float4 w4 = wreg[j], x4 = xp[j];
                s = fmaf(w4.x, x4.x, s); s = fmaf(w4.y, x4.y, s);
                s = fmaf(w4.z, x4.z, s); s = fmaf(w4.w, x4.w, s);
            }
            s += __shfl_xor(s, 1, 64);
            s += __shfl_xor(s, 2, 64);
            if (seg == 0) qvs[rr][oc] = s;
        }
    }

    // ---- hoist wprj slice (reused for both rounds, latency hidden) ----
    const int oc8  = tid >> 3;     // output column 0..127
    const int seg8 = tid & 7;      // 16-k slice
    const float4* wpp = (const float4*)(wprj + (size_t)oc8 * EDIM + seg8 * 16);
    float4 w4[4];
    #pragma unroll
    for (int j = 0; j < 4; ++j) w4[j] = wpp[j];

    __syncthreads();   // qvs ready

    const float SC = 0.25f * 1.44269504088896340736f;  // 1/sqrt(D) * log2(e)

    #pragma unroll
    for (int t = 0; t < 2; ++t) {
        const int row = t * 2 + r;            // local row 0..3
        float evs[8] = {epre[t][0].x, epre[t][0].y, epre[t][0].z, epre[t][0].w,
                        epre[t][1].x, epre[t][1].y, epre[t][1].z, epre[t][1].w};

        const float* qrow = qvs[row] + h * DDIM;         // LDS, wave-uniform
        const float* vrow = qvs[row] + 128 + h * DDIM;

        // ---- per-head precompute (wekv/bekv wave-uniform -> SGPRs) ----
        float wk[DDIM], bk[DDIM], cd[DDIM], wvv[DDIM], bv[DDIM];
        float qwk = 0.f;
        #pragma unroll
        for (int d = 0; d < DDIM; ++d) {
            float q = qrow[d];
            wk[d]  = wekv[h * DDIM + d];
            bk[d]  = bekv[h * DDIM + d];
            wvv[d] = wekv[EDIM + h * DDIM + d];
            bv[d]  = bekv[EDIM + h * DDIM + d];
            qwk    = fmaf(q, wk[d], qwk);
            cd[d]  = 0.495f * SC * q;
        }
        const float Alin = SC * 0.505f * qwk;

        // ---- fused pass over this lane's 8 m-values ----
        float racc[DDIM];
        #pragma unroll
        for (int d = 0; d < DDIM; ++d) racc[d] = 0.f;
        float sp = 0.f, spe = 0.f;
        #pragma unroll
        for (int c = 0; c < 8; ++c) {
            float s = evs[c];
            float dot = s * Alin;
            #pragma unroll
            for (int d = 0; d < DDIM; ++d) {
                float tt = fmaf(s, wk[d], bk[d]);
                dot = fmaf(cd[d], fabsf(tt), dot);
            }
            float p = __builtin_amdgcn_exp2f(dot);
            sp  += p;
            spe  = fmaf(p, s, spe);
            #pragma unroll
            for (int d = 0; d < DDIM; ++d) {
                float tt = fmaf(s, wvv[d], bv[d]);
                racc[d] = fmaf(p, fabsf(tt), racc[d]);   // 0.495 after reduce
            }
        }

        // ---- sp/spe butterfly ----
        #pragma unroll
        for (int off = 1; off < 64; off <<= 1) {
            sp  += __shfl_xor(sp,  off, 64);
            spe += __shfl_xor(spe, off, 64);
        }

        // ---- racc transpose reduce in own wave slice (no barrier) ----
        #pragma unroll
        for (int d = 0; d < DDIM; ++d)
            red[wv][d][lane] = racc[d];
        const int rc = lane & 15, rg = lane >> 4;
        float part = 0.f;
        #pragma unroll
        for (int j = 0; j < 16; ++j)
            part += red[wv][rc][rg * 16 + j];
        part += __shfl_xor(part, 16, 64);
        part += __shfl_xor(part, 32, 64);

        if (lane < DDIM) {
            float wvs = wekv[EDIM + h * DDIM + lane];
            float bvs = bekv[EDIM + h * DDIM + lane];
            float acc = 0.495f * part + 0.505f * fmaf(wvs, spe, bvs * sp);
            hat_s[t][r][h * DDIM + lane] = vrow[lane] + acc / sp;
        }
        __syncthreads();   // hat ready (double-buffered across rounds)

        // ---- output projection: both rows of this round ----
        const float4* h0 = (const float4*)(&hat_s[t][0][seg8 * 16]);
        const float4* h1 = (const float4*)(&hat_s[t][1][seg8 * 16]);
        float s0 = 0.f, s1 = 0.f;
        #pragma unroll
        for (int j = 0; j < 4; ++j) {
            float4 a = w4[j], p0 = h0[j], p1 = h1[j];
            s0 = fmaf(a.x, p0.x, s0); s0 = fmaf(a.y, p0.y, s0);
            s0 = fmaf(a.z, p0.z, s0); s0 = fmaf(a.w, p0.w, s0);
            s1 = fmaf(a.x, p1.x, s1); s1 = fmaf(a.y, p1.y, s1);
            s1 = fmaf(a.z, p1.z, s1); s1 = fmaf(a.w, p1.w, s1);
        }
        #pragma unroll
        for (int off = 1; off < 8; off <<= 1) {
            s0 += __shfl_xor(s0, off, 64);
            s1 += __shfl_xor(s1, off, 64);
        }
        if (seg8 < 2) {
            float v = (seg8 ? s1 : s0) + bprj[oc8];
            out[(size_t)(bn0 + t * 2 + seg8) * EDIM + oc8] = v;
        }
    }
}

// ---------------------------------------------------------------------------
extern "C" void kernel_launch(void* const* d_in, const int* in_sizes, int n_in,
                              void* d_out, int out_size, void* d_ws, size_t ws_size,
                              hipStream_t stream) {
    const float* x     = (const float*)d_in[0];  // [B,N,128]
    const float* e     = (const float*)d_in[1];  // [B,N,N]
    const float* w_qkv = (const float*)d_in[2];  // [384,128]
    const float* w_ekv = (const float*)d_in[3];  // [256,1]
    const float* b_ekv = (const float*)d_in[4];  // [256]
    const float* w_prj = (const float*)d_in[5];  // [128,128]
    const float* b_prj = (const float*)d_in[6];  // [128]
    float* out = (float*)d_out;

    attn_all<<<MROWS / 4, 1024, 0, stream>>>(x, e, w_qkv, w_ekv, b_ekv,
                                             w_prj, b_prj, out);
}